// Round 1
// baseline (451.937 us; speedup 1.0000x reference)
//
#include <hip/hip_runtime.h>
#include <math.h>

#define B_    32
#define C_IN  12
#define C_HID 16
#define H_    495
#define W_    436
#define HW    (H_ * W_)        // 215820 (divisible by 4)
#define NPIX  (B_ * HW)        // 6906240
#define NG    (NPIX / 4)       // 1726560 groups of 4 pixels

__global__ __launch_bounds__(256) void temporal_mlp_kernel(
    const float* __restrict__ x,
    const float* __restrict__ w1, const float* __restrict__ b1,
    const float* __restrict__ w2, const float* __restrict__ b2,
    const float* __restrict__ w3, const float* __restrict__ b3,
    float* __restrict__ out)
{
    // Weight staging: 497 floats, read as wave-uniform broadcasts (no bank conflicts).
    __shared__ __align__(16) float sW1[16][12];  // pre-scaled by 1/255 (folds x/255)
    __shared__ __align__(16) float sB1[16];      // b1 - 0.5*rowsum(w1) (folds -0.5)
    __shared__ __align__(16) float sW2[16][16];
    __shared__ __align__(16) float sB2[16];
    __shared__ __align__(16) float sW3[16];
    __shared__ float sB3;

    const int tid = threadIdx.x;
    if (tid < 192) sW1[tid / 12][tid % 12] = w1[tid] * (1.0f / 255.0f);
    sW2[tid / 16][tid % 16] = w2[tid];           // exactly 256 elements
    if (tid < 16) {
        float s = 0.0f;
        #pragma unroll
        for (int c = 0; c < 12; ++c) s += w1[tid * 12 + c];
        sB1[tid] = b1[tid] - 0.5f * s;
        sB2[tid] = b2[tid];
        sW3[tid] = w3[tid];
    }
    if (tid == 0) sB3 = b3[0];
    __syncthreads();

    const int g = blockIdx.x * 256 + tid;
    if (g >= NG) return;

    const int base = g * 4;                  // flat pixel index over [B, H*W]
    const int b    = base / HW;
    const int p    = base - b * HW;
    const float* xb = x + (size_t)b * (C_IN * HW) + p;

    // 12 coalesced float4 loads (one per input channel plane)
    float xin0[12], xin1[12], xin2[12], xin3[12];
    #pragma unroll
    for (int c = 0; c < 12; ++c) {
        float4 t = *(const float4*)(xb + (size_t)c * HW);
        xin0[c] = t.x; xin1[c] = t.y; xin2[c] = t.z; xin3[c] = t.w;
    }

    // ---- layer 1: 12 -> 16, relu (normalization folded into sW1/sB1) ----
    float h10[16], h11[16], h12[16], h13[16];
    #pragma unroll
    for (int o = 0; o < 16; ++o) {
        float wr[12];
        ((float4*)wr)[0] = ((const float4*)(&sW1[o][0]))[0];
        ((float4*)wr)[1] = ((const float4*)(&sW1[o][0]))[1];
        ((float4*)wr)[2] = ((const float4*)(&sW1[o][0]))[2];
        const float bb = sB1[o];
        float a0 = bb, a1 = bb, a2 = bb, a3 = bb;
        #pragma unroll
        for (int c = 0; c < 12; ++c) {
            a0 = fmaf(xin0[c], wr[c], a0);
            a1 = fmaf(xin1[c], wr[c], a1);
            a2 = fmaf(xin2[c], wr[c], a2);
            a3 = fmaf(xin3[c], wr[c], a3);
        }
        h10[o] = fmaxf(a0, 0.0f); h11[o] = fmaxf(a1, 0.0f);
        h12[o] = fmaxf(a2, 0.0f); h13[o] = fmaxf(a3, 0.0f);
    }

    // ---- layer 2: 16 -> 16, relu ----
    float h20[16], h21[16], h22[16], h23[16];
    #pragma unroll
    for (int o = 0; o < 16; ++o) {
        float wr[16];
        ((float4*)wr)[0] = ((const float4*)(&sW2[o][0]))[0];
        ((float4*)wr)[1] = ((const float4*)(&sW2[o][0]))[1];
        ((float4*)wr)[2] = ((const float4*)(&sW2[o][0]))[2];
        ((float4*)wr)[3] = ((const float4*)(&sW2[o][0]))[3];
        const float bb = sB2[o];
        float a0 = bb, a1 = bb, a2 = bb, a3 = bb;
        #pragma unroll
        for (int c = 0; c < 16; ++c) {
            a0 = fmaf(h10[c], wr[c], a0);
            a1 = fmaf(h11[c], wr[c], a1);
            a2 = fmaf(h12[c], wr[c], a2);
            a3 = fmaf(h13[c], wr[c], a3);
        }
        h20[o] = fmaxf(a0, 0.0f); h21[o] = fmaxf(a1, 0.0f);
        h22[o] = fmaxf(a2, 0.0f); h23[o] = fmaxf(a3, 0.0f);
    }

    // ---- layer 3: 16 -> 1, sigmoid, *255 ----
    float wr[16];
    ((float4*)wr)[0] = ((const float4*)(&sW3[0]))[0];
    ((float4*)wr)[1] = ((const float4*)(&sW3[0]))[1];
    ((float4*)wr)[2] = ((const float4*)(&sW3[0]))[2];
    ((float4*)wr)[3] = ((const float4*)(&sW3[0]))[3];
    const float b3v = sB3;
    float t0 = b3v, t1 = b3v, t2 = b3v, t3 = b3v;
    #pragma unroll
    for (int c = 0; c < 16; ++c) {
        t0 = fmaf(h20[c], wr[c], t0);
        t1 = fmaf(h21[c], wr[c], t1);
        t2 = fmaf(h22[c], wr[c], t2);
        t3 = fmaf(h23[c], wr[c], t3);
    }
    float4 r;
    r.x = 255.0f / (1.0f + __expf(-t0));
    r.y = 255.0f / (1.0f + __expf(-t1));
    r.z = 255.0f / (1.0f + __expf(-t2));
    r.w = 255.0f / (1.0f + __expf(-t3));
    *(float4*)(out + base) = r;
}

extern "C" void kernel_launch(void* const* d_in, const int* in_sizes, int n_in,
                              void* d_out, int out_size, void* d_ws, size_t ws_size,
                              hipStream_t stream) {
    const float* x  = (const float*)d_in[0];
    const float* w1 = (const float*)d_in[1];
    const float* b1 = (const float*)d_in[2];
    const float* w2 = (const float*)d_in[3];
    const float* b2 = (const float*)d_in[4];
    const float* w3 = (const float*)d_in[5];
    const float* b3 = (const float*)d_in[6];
    float* out = (float*)d_out;

    const int grid = (NG + 255) / 256;  // 6745 blocks of 256
    temporal_mlp_kernel<<<grid, 256, 0, stream>>>(x, w1, b1, w2, b2, w3, b3, out);
}